// Round 3
// baseline (207.009 us; speedup 1.0000x reference)
//
#include <hip/hip_runtime.h>
#include <math.h>

#define N_ENTITY 200000
#define N_REL 32
#define DIM 64
#define N_HOP 2
#define N_MEM 32
#define BATCH 1024
#define PAIR_PER_HOP (BATCH * N_MEM)       // 32768
#define N_PAIR (N_HOP * PAIR_PER_HOP)      // 65536
#define CAP 3072                           // per-relation bucket capacity (mean 2048, sigma ~45)
#define BPR 128                            // blocks (waves) per relation in pairs kernel
#define NBLK_PAIRS (BPR * N_REL)           // 4096

__device__ __forceinline__ float wave_reduce_sum(float v) {
    v += __shfl_xor(v, 1);
    v += __shfl_xor(v, 2);
    v += __shfl_xor(v, 4);
    v += __shfl_xor(v, 8);
    v += __shfl_xor(v, 16);
    v += __shfl_xor(v, 32);
    return v;
}

__device__ __forceinline__ float sigmoidf_(float x) {
    return 1.f / (1.f + expf(-x));
}

// ---------------------------------------------------------------------------
// K0: bucket pair indices by relation. 64 blocks x 256 threads, 4 pairs/thread.
// g_cnt must be zeroed before launch (hipMemsetAsync).
// ---------------------------------------------------------------------------
__global__ __launch_bounds__(256) void ripple_bin(
    const int* __restrict__ mr,
    int* __restrict__ g_cnt,     // [N_REL]
    int* __restrict__ list)      // [N_REL][CAP]
{
    __shared__ int hist[N_REL];
    __shared__ int cur[N_REL];
    const int tid = (int)threadIdx.x;
    const int pbase = (int)blockIdx.x * 1024;

    if (tid < N_REL) hist[tid] = 0;
    __syncthreads();

    int rv[4];
    #pragma unroll
    for (int u = 0; u < 4; ++u) {
        rv[u] = mr[pbase + u * 256 + tid];
        atomicAdd(&hist[rv[u]], 1);
    }
    __syncthreads();
    if (tid < N_REL) cur[tid] = atomicAdd(&g_cnt[tid], hist[tid]);
    __syncthreads();
    #pragma unroll
    for (int u = 0; u < 4; ++u) {
        const int r = rv[u];
        const int pos = atomicAdd(&cur[r], 1);
        if (pos < CAP) list[r * CAP + pos] = pbase + u * 256 + tid;
    }
}

// ---------------------------------------------------------------------------
// K1: relation-bucketed pair kernel. One wave per block; block (j, r) handles
// bucket-r pairs at positions j, j+BPR, ... R_r in VGPRs (lane = row).
// Pairs processed in groups of 4: loads/FMAs for 4 pairs in flight, then 4
// interleaved butterfly reductions for the KGE scalar (hides shfl latency).
// Stores Rh for ALL pairs (hop0 logits computed later in attn).
// ---------------------------------------------------------------------------
__global__ __launch_bounds__(64) void ripple_pairs(
    const int* __restrict__ mh,
    const int* __restrict__ mt,
    const float* __restrict__ item_table,
    const float* __restrict__ rel_table,
    const int* __restrict__ g_cnt,
    const int* __restrict__ list,
    float* __restrict__ wsRh,     // [N_PAIR][DIM]
    float* __restrict__ ws_kge,   // [NBLK_PAIRS]
    float* __restrict__ ws_l2)    // [NBLK_PAIRS]
{
    const int lane = (int)threadIdx.x;
    const int j = (int)blockIdx.x;
    const int r = (int)blockIdx.y;
    const int n = min(g_cnt[r], CAP);

    // R row `lane` -> 64 VGPRs, one L2 read per wave
    float R[DIM];
    const float* __restrict__ Rrow =
        rel_table + (size_t)r * (DIM * DIM) + (size_t)lane * DIM;
    #pragma unroll
    for (int k = 0; k < DIM; k += 4) {
        const float4 q = *(const float4*)(Rrow + k);
        R[k] = q.x; R[k + 1] = q.y; R[k + 2] = q.z; R[k + 3] = q.w;
    }
    float rsq = 0.f;
    #pragma unroll
    for (int k = 0; k < DIM; ++k) rsq = fmaf(R[k], R[k], rsq);

    float kge = 0.f;    // lane-uniform accumulator
    float l2ht = 0.f;   // per-lane accumulator
    int cnt = 0;

    for (int i0 = j; i0 < n; i0 += 4 * BPR) {
        float z[4];
        #pragma unroll
        for (int u = 0; u < 4; ++u) {
            z[u] = 0.f;
            const int i = i0 + u * BPR;
            if (i < n) {
                const int p = __builtin_amdgcn_readfirstlane(list[r * CAP + i]);
                const int hidx = __builtin_amdgcn_readfirstlane(mh[p]);
                const int tidx = __builtin_amdgcn_readfirstlane(mt[p]);
                const float* __restrict__ hp = item_table + (size_t)hidx * DIM;
                const float* __restrict__ tp = item_table + (size_t)tidx * DIM;
                const float hl = hp[lane];   // per-lane, coalesced
                const float tl = tp[lane];

                float rh0 = 0.f, rh1 = 0.f, rh2 = 0.f, rh3 = 0.f;
                float rt0 = 0.f, rt1 = 0.f, rt2 = 0.f, rt3 = 0.f;
                #pragma unroll
                for (int k = 0; k < DIM; k += 4) {
                    const float4 h4 = *(const float4*)(hp + k);  // uniform addr
                    const float4 t4 = *(const float4*)(tp + k);
                    rh0 = fmaf(R[k],     h4.x, rh0);
                    rh1 = fmaf(R[k + 1], h4.y, rh1);
                    rh2 = fmaf(R[k + 2], h4.z, rh2);
                    rh3 = fmaf(R[k + 3], h4.w, rh3);
                    rt0 = fmaf(R[k],     t4.x, rt0);
                    rt1 = fmaf(R[k + 1], t4.y, rt1);
                    rt2 = fmaf(R[k + 2], t4.z, rt2);
                    rt3 = fmaf(R[k + 3], t4.w, rt3);
                }
                const float rhv = (rh0 + rh1) + (rh2 + rh3);   // (R h)_lane
                const float rtv = (rt0 + rt1) + (rt2 + rt3);   // (R t)_lane
                wsRh[(size_t)p * DIM + lane] = rhv;
                z[u] = hl * rtv;                               // hRt partial
                l2ht += hl * hl + tl * tl;
                ++cnt;
            }
        }
        // 4 interleaved butterfly reductions (independent chains -> ILP)
        #pragma unroll
        for (int s = 1; s <= 32; s <<= 1) {
            #pragma unroll
            for (int u = 0; u < 4; ++u) z[u] += __shfl_xor(z[u], s);
        }
        #pragma unroll
        for (int u = 0; u < 4; ++u) {
            if (i0 + u * BPR < n) kge += sigmoidf_(z[u]);
        }
    }

    const float l2tot = wave_reduce_sum(fmaf((float)cnt, rsq, l2ht));
    if (lane == 0) {
        const int bid = r * BPR + j;
        ws_kge[bid] = kge;
        ws_l2[bid] = l2tot;
    }
}

// ---------------------------------------------------------------------------
// K2: per-batch attention chain. Both hops' logits from wsRh . v.
// ---------------------------------------------------------------------------
__global__ __launch_bounds__(256) void ripple_attn(
    const int* __restrict__ items,
    const float* __restrict__ labels,
    const int* __restrict__ mt,
    const float* __restrict__ item_table,
    const float* __restrict__ W,
    const float* __restrict__ wsRh,
    float* __restrict__ out,
    float* __restrict__ ws_bce)
{
    __shared__ float sAtt[N_MEM];
    __shared__ __align__(16) float sO[4][DIM];
    __shared__ __align__(16) float sU[DIM];

    const int b = (int)blockIdx.x;
    const int tid = (int)threadIdx.x;
    const int lane = tid & 63;
    const int w = tid >> 6;

    float v_i = item_table[(size_t)items[b] * DIM + lane];
    float y_i = 0.f;

    for (int hop = 0; hop < N_HOP; ++hop) {
        #pragma unroll
        for (int q = 0; q < 8; ++q) {
            const int m = w * 8 + q;
            const float rh =
                wsRh[(size_t)(hop * PAIR_PER_HOP + b * N_MEM + m) * DIM + lane];
            const float att = wave_reduce_sum(rh * v_i);
            if (lane == 0) sAtt[m] = att;
        }
        __syncthreads();

        float mx = -1e30f;
        #pragma unroll
        for (int m = 0; m < N_MEM; ++m) mx = fmaxf(mx, sAtt[m]);
        float se = 0.f;
        float e_loc[8];
        #pragma unroll
        for (int m = 0; m < N_MEM; ++m) {
            const float e = expf(sAtt[m] - mx);
            se += e;
            if ((m >> 3) == w) e_loc[m & 7] = e;
        }
        const float inv = 1.f / se;

        float op = 0.f;
        #pragma unroll
        for (int q = 0; q < 8; ++q) {
            const int m = w * 8 + q;
            const int tidx = mt[hop * PAIR_PER_HOP + b * N_MEM + m];
            op = fmaf(item_table[(size_t)tidx * DIM + lane], e_loc[q] * inv, op);
        }
        sO[w][lane] = op;
        __syncthreads();

        const float o_i = sO[0][lane] + sO[1][lane] + sO[2][lane] + sO[3][lane];
        y_i += o_i;
        if (w == 0) sU[lane] = v_i + o_i;
        __syncthreads();

        const float4* __restrict__ Wrow = (const float4*)(W + (size_t)lane * DIM);
        float a0 = 0.f, a1 = 0.f, a2 = 0.f, a3 = 0.f;
        #pragma unroll
        for (int k = 0; k < 16; ++k) {
            const float4 w4 = Wrow[k];
            const float4 u4 = *(const float4*)&sU[k * 4];
            a0 = fmaf(w4.x, u4.x, a0);
            a1 = fmaf(w4.y, u4.y, a1);
            a2 = fmaf(w4.z, u4.z, a2);
            a3 = fmaf(w4.w, u4.w, a3);
        }
        v_i = (a0 + a1) + (a2 + a3);
        __syncthreads();
    }

    float s = wave_reduce_sum(v_i * y_i);
    s = 1.f / (1.f + expf(-s));
    if (tid == 0) {
        out[b] = s;
        const float lab = labels[b];
        const float logp = fmaxf(logf(s), -100.f);
        const float lognp = fmaxf(logf(1.f - s), -100.f);
        ws_bce[b] = lab * logp + (1.f - lab) * lognp;
    }
}

// ---------------------------------------------------------------------------
// K3: loss finalize.
// ---------------------------------------------------------------------------
__global__ __launch_bounds__(256) void ripple_finalize(
    const float* __restrict__ ws_bce,
    const float* __restrict__ ws_kge,
    const float* __restrict__ ws_l2,
    float* __restrict__ out)
{
    __shared__ float sb[4], sk[4], sl[4];
    const int tid = (int)threadIdx.x;
    float bsum = 0.f, ksum = 0.f, lsum = 0.f;
    for (int i = tid; i < BATCH; i += 256) bsum += ws_bce[i];
    for (int i = tid; i < NBLK_PAIRS; i += 256) {
        ksum += ws_kge[i];
        lsum += ws_l2[i];
    }
    bsum = wave_reduce_sum(bsum);
    ksum = wave_reduce_sum(ksum);
    lsum = wave_reduce_sum(lsum);
    const int w = tid >> 6;
    if ((tid & 63) == 0) { sb[w] = bsum; sk[w] = ksum; sl[w] = lsum; }
    __syncthreads();
    if (tid == 0) {
        const float bs = sb[0] + sb[1] + sb[2] + sb[3];
        const float ks = sk[0] + sk[1] + sk[2] + sk[3];
        const float ls = sl[0] + sl[1] + sl[2] + sl[3];
        const float base_loss = -bs / (float)BATCH;
        const float kge_loss = -0.01f * (ks / (float)(BATCH * N_MEM));
        const float l2_loss = 1e-7f * ls;
        out[BATCH + 0] = base_loss + kge_loss + l2_loss;
        out[BATCH + 1] = base_loss;
        out[BATCH + 2] = kge_loss;
        out[BATCH + 3] = l2_loss;
    }
}

extern "C" void kernel_launch(void* const* d_in, const int* in_sizes, int n_in,
                              void* d_out, int out_size, void* d_ws, size_t ws_size,
                              hipStream_t stream) {
    const int* items        = (const int*)d_in[0];
    const float* labels     = (const float*)d_in[1];
    const int* mh           = (const int*)d_in[2];
    const int* mr           = (const int*)d_in[3];
    const int* mt           = (const int*)d_in[4];
    const float* item_table = (const float*)d_in[5];
    const float* rel_table  = (const float*)d_in[6];
    const float* W          = (const float*)d_in[7];
    float* out = (float*)d_out;

    // workspace layout (floats/ints, all 4B-aligned):
    //   wsRh   [N_PAIR*DIM]  16.78 MB
    //   list   [N_REL*CAP]   384 KB (int)
    //   g_cnt  [N_REL]       (int)
    //   ws_bce [BATCH]
    //   ws_kge [NBLK_PAIRS]
    //   ws_l2  [NBLK_PAIRS]
    float* ws = (float*)d_ws;
    float* wsRh   = ws;
    int*   list   = (int*)(wsRh + (size_t)N_PAIR * DIM);
    int*   g_cnt  = list + N_REL * CAP;
    float* ws_bce = (float*)(g_cnt + N_REL);
    float* ws_kge = ws_bce + BATCH;
    float* ws_l2  = ws_kge + NBLK_PAIRS;

    hipMemsetAsync(g_cnt, 0, N_REL * sizeof(int), stream);
    ripple_bin<<<N_PAIR / 1024, 256, 0, stream>>>(mr, g_cnt, list);
    dim3 gpairs(BPR, N_REL);
    ripple_pairs<<<gpairs, 64, 0, stream>>>(mh, mt, item_table, rel_table,
                                            g_cnt, list, wsRh, ws_kge, ws_l2);
    ripple_attn<<<BATCH, 256, 0, stream>>>(items, labels, mt, item_table, W,
                                           wsRh, out, ws_bce);
    ripple_finalize<<<1, 256, 0, stream>>>(ws_bce, ws_kge, ws_l2, out);
}

// Round 4
// 162.915 us; speedup vs baseline: 1.2707x; 1.2707x over previous
//
#include <hip/hip_runtime.h>
#include <math.h>

#define N_ENTITY 200000
#define N_REL 32
#define DIM 64
#define N_HOP 2
#define N_MEM 32
#define BATCH 1024
#define PAIR_PER_HOP (BATCH * N_MEM)       // 32768
#define N_PAIR (N_HOP * PAIR_PER_HOP)      // 65536
#define CAP 3072                           // per-relation bucket capacity (mean 2048)
#define JBLK 32                            // blocks per relation in pairs kernel
#define WPB 4                              // waves per block
#define NBLK_PAIRS (JBLK * N_REL * WPB)    // 4096 per-wave reduction slots

typedef __attribute__((ext_vector_type(8))) short short8;   // 8 bf16 (A/B frag)
typedef __attribute__((ext_vector_type(4))) float floatx4;  // C/D frag

__device__ __forceinline__ float wave_reduce_sum(float v) {
    v += __shfl_xor(v, 1);
    v += __shfl_xor(v, 2);
    v += __shfl_xor(v, 4);
    v += __shfl_xor(v, 8);
    v += __shfl_xor(v, 16);
    v += __shfl_xor(v, 32);
    return v;
}

__device__ __forceinline__ unsigned short f2b(float x) {
    // fp32 -> bf16 round-to-nearest-even (inputs are well-behaved normals)
    union { float f; unsigned u; } c; c.f = x;
    const unsigned r = (c.u + 0x7FFFu + ((c.u >> 16) & 1u)) >> 16;
    return (unsigned short)r;
}

__device__ __forceinline__ short8 pack8(const float4 a, const float4 b) {
    short8 s;
    s[0] = (short)f2b(a.x); s[1] = (short)f2b(a.y);
    s[2] = (short)f2b(a.z); s[3] = (short)f2b(a.w);
    s[4] = (short)f2b(b.x); s[5] = (short)f2b(b.y);
    s[6] = (short)f2b(b.z); s[7] = (short)f2b(b.w);
    return s;
}

__device__ __forceinline__ float sq4(const float4 a) {
    return a.x * a.x + a.y * a.y + a.z * a.z + a.w * a.w;
}

// ---------------------------------------------------------------------------
// K0: bucket pair indices by relation (unchanged from R3; g_cnt zeroed first).
// ---------------------------------------------------------------------------
__global__ __launch_bounds__(256) void ripple_bin(
    const int* __restrict__ mr,
    int* __restrict__ g_cnt,     // [N_REL]
    int* __restrict__ list)      // [N_REL][CAP]
{
    __shared__ int hist[N_REL];
    __shared__ int cur[N_REL];
    const int tid = (int)threadIdx.x;
    const int pbase = (int)blockIdx.x * 1024;

    if (tid < N_REL) hist[tid] = 0;
    __syncthreads();

    int rv[4];
    #pragma unroll
    for (int u = 0; u < 4; ++u) {
        rv[u] = mr[pbase + u * 256 + tid];
        atomicAdd(&hist[rv[u]], 1);
    }
    __syncthreads();
    if (tid < N_REL) cur[tid] = atomicAdd(&g_cnt[tid], hist[tid]);
    __syncthreads();
    #pragma unroll
    for (int u = 0; u < 4; ++u) {
        const int r = rv[u];
        const int pos = atomicAdd(&cur[r], 1);
        if (pos < CAP) list[r * CAP + pos] = pbase + u * 256 + tid;
    }
}

// ---------------------------------------------------------------------------
// K1: MFMA gather-GEMM pairs kernel.
// Block (j, r), 4 independent waves. Wave handles 16-pair tiles tau =
// j*4+w, +128, ... of relation r's bucket. Per tile:
//   A_h/A_t (16x64) loaded straight from item_table in A-frag layout,
//   B = R^T held in 32 VGPRs (bf16), 16x mfma_f32_16x16x32_bf16 ->
//   Rh (stored to wsRh) and Rt (consumed by hRt for the KGE term).
// MFMA layouts (guide §3, m89/m91): A[m=l&15][k=8*(l>>4)+j];
// B[k=8*(l>>4)+j][n=l&15]; C row=(l>>4)*4+reg, col=l&15.
// ---------------------------------------------------------------------------
__global__ __launch_bounds__(256) void ripple_pairs(
    const int* __restrict__ mh,
    const int* __restrict__ mt,
    const float* __restrict__ item_table,
    const float* __restrict__ rel_table,
    const int* __restrict__ g_cnt,
    const int* __restrict__ list,
    float* __restrict__ wsRh,     // [N_PAIR][DIM]
    float* __restrict__ ws_kge,   // [NBLK_PAIRS]
    float* __restrict__ ws_l2)    // [NBLK_PAIRS]
{
    const int tid = (int)threadIdx.x;
    const int lane = tid & 63;
    const int w = tid >> 6;
    const int j = (int)blockIdx.x;
    const int r = (int)blockIdx.y;
    const int n = min(g_cnt[r], CAP);

    const int m16 = lane & 15;          // m (A row) / n (B col) / C col
    const int quad = lane >> 4;         // k-group

    // ---- B = R^T fragments: Bf[s][tn], lane holds R[n][k0..k0+7] ----
    short8 Bf[2][4];
    float rsq = 0.f;
    {
        const float* __restrict__ Rb = rel_table + (size_t)r * (DIM * DIM);
        #pragma unroll
        for (int s = 0; s < 2; ++s) {
            #pragma unroll
            for (int tn = 0; tn < 4; ++tn) {
                const float* src = Rb + (size_t)(16 * tn + m16) * DIM + 32 * s + 8 * quad;
                const float4 a = *(const float4*)src;
                const float4 b = *(const float4*)(src + 4);
                rsq += sq4(a) + sq4(b);   // exact fp32 ||R||^2, full coverage
                Bf[s][tn] = pack8(a, b);
            }
        }
    }

    float kge = 0.f;
    float l2ht = 0.f;
    int cnt = 0;

    const int rb = r * CAP;
    const int wave_id = j * WPB + w;    // 0..127 within relation

    for (int tau = wave_id; tau * 16 < n; tau += JBLK * WPB) {
        const int base = tau * 16;
        const int pos = min(base + m16, n - 1);     // clamp tail (dup benign)
        const int p = list[rb + pos];
        const int hidx = mh[p];
        const int tidx = mt[p];
        const bool mvalid = (base + m16) < n;

        // ---- A fragments straight from global in frag layout ----
        const float* __restrict__ hp = item_table + (size_t)hidx * DIM + 8 * quad;
        const float* __restrict__ tp = item_table + (size_t)tidx * DIM + 8 * quad;
        const float4 h0a = *(const float4*)hp;
        const float4 h0b = *(const float4*)(hp + 4);
        const float4 h1a = *(const float4*)(hp + 32);
        const float4 h1b = *(const float4*)(hp + 36);
        const float4 t0a = *(const float4*)tp;
        const float4 t0b = *(const float4*)(tp + 4);
        const float4 t1a = *(const float4*)(tp + 32);
        const float4 t1b = *(const float4*)(tp + 36);

        if (mvalid) {   // exact fp32 h^2 + t^2 (each elem covered once)
            l2ht += sq4(h0a) + sq4(h0b) + sq4(h1a) + sq4(h1b)
                  + sq4(t0a) + sq4(t0b) + sq4(t1a) + sq4(t1b);
        }

        const short8 Ah0 = pack8(h0a, h0b);
        const short8 Ah1 = pack8(h1a, h1b);
        const short8 At0 = pack8(t0a, t0b);
        const short8 At1 = pack8(t1a, t1b);

        // ---- 16 MFMAs: Rh and Rt, 4 n-tiles x 2 k-steps ----
        floatx4 Ch[4], Ct[4];
        const floatx4 z4 = {0.f, 0.f, 0.f, 0.f};
        #pragma unroll
        for (int tn = 0; tn < 4; ++tn) {
            Ch[tn] = __builtin_amdgcn_mfma_f32_16x16x32_bf16(Ah0, Bf[0][tn], z4, 0, 0, 0);
            Ch[tn] = __builtin_amdgcn_mfma_f32_16x16x32_bf16(Ah1, Bf[1][tn], Ch[tn], 0, 0, 0);
            Ct[tn] = __builtin_amdgcn_mfma_f32_16x16x32_bf16(At0, Bf[0][tn], z4, 0, 0, 0);
            Ct[tn] = __builtin_amdgcn_mfma_f32_16x16x32_bf16(At1, Bf[1][tn], Ct[tn], 0, 0, 0);
        }

        // ---- redistribute indices into C layout (slot = 4*quad + q) ----
        int pq[4], hq[4];
        #pragma unroll
        for (int q = 0; q < 4; ++q) {
            pq[q] = __shfl(p, 4 * quad + q);
            hq[q] = __shfl(hidx, 4 * quad + q);
        }

        // ---- hRt = h . (R t) from Ct frags + L1-hot scattered h reloads ----
        float acc[4] = {0.f, 0.f, 0.f, 0.f};
        #pragma unroll
        for (int tn = 0; tn < 4; ++tn) {
            #pragma unroll
            for (int q = 0; q < 4; ++q) {
                const float hv = item_table[(size_t)hq[q] * DIM + m16 + 16 * tn];
                acc[q] = fmaf(hv, Ct[tn][q], acc[q]);
            }
        }
        #pragma unroll
        for (int s = 1; s <= 8; s <<= 1) {   // reduce within 16-lane groups
            #pragma unroll
            for (int q = 0; q < 4; ++q) acc[q] += __shfl_xor(acc[q], s);
        }
        #pragma unroll
        for (int q = 0; q < 4; ++q) {
            const bool pv = (base + 4 * quad + q) < n;
            const float sg = 1.f / (1.f + expf(-acc[q]));
            if (pv && m16 == 0) kge += sg;
        }

        // ---- store Rh (dup stores for padded slots write identical data) ----
        #pragma unroll
        for (int tn = 0; tn < 4; ++tn) {
            #pragma unroll
            for (int q = 0; q < 4; ++q) {
                wsRh[(size_t)pq[q] * DIM + m16 + 16 * tn] = Ch[tn][q];
            }
        }

        cnt += min(16, n - base);
    }

    // ---- per-wave reductions ----
    const float Rsum = wave_reduce_sum(rsq);              // uniform ||R_r||^2
    const float l2tot = wave_reduce_sum(l2ht) + (float)cnt * Rsum;
    const float kgetot = wave_reduce_sum(kge);
    if (lane == 0) {
        const int bid = (r * JBLK + j) * WPB + w;
        ws_kge[bid] = kgetot;
        ws_l2[bid] = l2tot;
    }
}

// ---------------------------------------------------------------------------
// K2: per-batch attention chain (unchanged from R3).
// ---------------------------------------------------------------------------
__global__ __launch_bounds__(256) void ripple_attn(
    const int* __restrict__ items,
    const float* __restrict__ labels,
    const int* __restrict__ mt,
    const float* __restrict__ item_table,
    const float* __restrict__ W,
    const float* __restrict__ wsRh,
    float* __restrict__ out,
    float* __restrict__ ws_bce)
{
    __shared__ float sAtt[N_MEM];
    __shared__ __align__(16) float sO[4][DIM];
    __shared__ __align__(16) float sU[DIM];

    const int b = (int)blockIdx.x;
    const int tid = (int)threadIdx.x;
    const int lane = tid & 63;
    const int w = tid >> 6;

    float v_i = item_table[(size_t)items[b] * DIM + lane];
    float y_i = 0.f;

    for (int hop = 0; hop < N_HOP; ++hop) {
        #pragma unroll
        for (int q = 0; q < 8; ++q) {
            const int m = w * 8 + q;
            const float rh =
                wsRh[(size_t)(hop * PAIR_PER_HOP + b * N_MEM + m) * DIM + lane];
            const float att = wave_reduce_sum(rh * v_i);
            if (lane == 0) sAtt[m] = att;
        }
        __syncthreads();

        float mx = -1e30f;
        #pragma unroll
        for (int m = 0; m < N_MEM; ++m) mx = fmaxf(mx, sAtt[m]);
        float se = 0.f;
        float e_loc[8];
        #pragma unroll
        for (int m = 0; m < N_MEM; ++m) {
            const float e = expf(sAtt[m] - mx);
            se += e;
            if ((m >> 3) == w) e_loc[m & 7] = e;
        }
        const float inv = 1.f / se;

        float op = 0.f;
        #pragma unroll
        for (int q = 0; q < 8; ++q) {
            const int m = w * 8 + q;
            const int tidx = mt[hop * PAIR_PER_HOP + b * N_MEM + m];
            op = fmaf(item_table[(size_t)tidx * DIM + lane], e_loc[q] * inv, op);
        }
        sO[w][lane] = op;
        __syncthreads();

        const float o_i = sO[0][lane] + sO[1][lane] + sO[2][lane] + sO[3][lane];
        y_i += o_i;
        if (w == 0) sU[lane] = v_i + o_i;
        __syncthreads();

        const float4* __restrict__ Wrow = (const float4*)(W + (size_t)lane * DIM);
        float a0 = 0.f, a1 = 0.f, a2 = 0.f, a3 = 0.f;
        #pragma unroll
        for (int k = 0; k < 16; ++k) {
            const float4 w4 = Wrow[k];
            const float4 u4 = *(const float4*)&sU[k * 4];
            a0 = fmaf(w4.x, u4.x, a0);
            a1 = fmaf(w4.y, u4.y, a1);
            a2 = fmaf(w4.z, u4.z, a2);
            a3 = fmaf(w4.w, u4.w, a3);
        }
        v_i = (a0 + a1) + (a2 + a3);
        __syncthreads();
    }

    float s = wave_reduce_sum(v_i * y_i);
    s = 1.f / (1.f + expf(-s));
    if (tid == 0) {
        out[b] = s;
        const float lab = labels[b];
        const float logp = fmaxf(logf(s), -100.f);
        const float lognp = fmaxf(logf(1.f - s), -100.f);
        ws_bce[b] = lab * logp + (1.f - lab) * lognp;
    }
}

// ---------------------------------------------------------------------------
// K3: loss finalize.
// ---------------------------------------------------------------------------
__global__ __launch_bounds__(256) void ripple_finalize(
    const float* __restrict__ ws_bce,
    const float* __restrict__ ws_kge,
    const float* __restrict__ ws_l2,
    float* __restrict__ out)
{
    __shared__ float sb[4], sk[4], sl[4];
    const int tid = (int)threadIdx.x;
    float bsum = 0.f, ksum = 0.f, lsum = 0.f;
    for (int i = tid; i < BATCH; i += 256) bsum += ws_bce[i];
    for (int i = tid; i < NBLK_PAIRS; i += 256) {
        ksum += ws_kge[i];
        lsum += ws_l2[i];
    }
    bsum = wave_reduce_sum(bsum);
    ksum = wave_reduce_sum(ksum);
    lsum = wave_reduce_sum(lsum);
    const int w = tid >> 6;
    if ((tid & 63) == 0) { sb[w] = bsum; sk[w] = ksum; sl[w] = lsum; }
    __syncthreads();
    if (tid == 0) {
        const float bs = sb[0] + sb[1] + sb[2] + sb[3];
        const float ks = sk[0] + sk[1] + sk[2] + sk[3];
        const float ls = sl[0] + sl[1] + sl[2] + sl[3];
        const float base_loss = -bs / (float)BATCH;
        const float kge_loss = -0.01f * (ks / (float)(BATCH * N_MEM));
        const float l2_loss = 1e-7f * ls;
        out[BATCH + 0] = base_loss + kge_loss + l2_loss;
        out[BATCH + 1] = base_loss;
        out[BATCH + 2] = kge_loss;
        out[BATCH + 3] = l2_loss;
    }
}

extern "C" void kernel_launch(void* const* d_in, const int* in_sizes, int n_in,
                              void* d_out, int out_size, void* d_ws, size_t ws_size,
                              hipStream_t stream) {
    const int* items        = (const int*)d_in[0];
    const float* labels     = (const float*)d_in[1];
    const int* mh           = (const int*)d_in[2];
    const int* mr           = (const int*)d_in[3];
    const int* mt           = (const int*)d_in[4];
    const float* item_table = (const float*)d_in[5];
    const float* rel_table  = (const float*)d_in[6];
    const float* W          = (const float*)d_in[7];
    float* out = (float*)d_out;

    // workspace: wsRh[N_PAIR*DIM] | list[N_REL*CAP] | g_cnt[N_REL] |
    //            ws_bce[BATCH] | ws_kge[NBLK_PAIRS] | ws_l2[NBLK_PAIRS]
    float* ws = (float*)d_ws;
    float* wsRh   = ws;
    int*   list   = (int*)(wsRh + (size_t)N_PAIR * DIM);
    int*   g_cnt  = list + N_REL * CAP;
    float* ws_bce = (float*)(g_cnt + N_REL);
    float* ws_kge = ws_bce + BATCH;
    float* ws_l2  = ws_kge + NBLK_PAIRS;

    hipMemsetAsync(g_cnt, 0, N_REL * sizeof(int), stream);
    ripple_bin<<<N_PAIR / 1024, 256, 0, stream>>>(mr, g_cnt, list);
    dim3 gpairs(JBLK, N_REL);
    ripple_pairs<<<gpairs, 256, 0, stream>>>(mh, mt, item_table, rel_table,
                                             g_cnt, list, wsRh, ws_kge, ws_l2);
    ripple_attn<<<BATCH, 256, 0, stream>>>(items, labels, mt, item_table, W,
                                           wsRh, out, ws_bce);
    ripple_finalize<<<1, 256, 0, stream>>>(ws_bce, ws_kge, ws_l2, out);
}

// Round 5
// 151.842 us; speedup vs baseline: 1.3633x; 1.0729x over previous
//
#include <hip/hip_runtime.h>
#include <math.h>

#define N_ENTITY 200000
#define N_REL 32
#define DIM 64
#define N_HOP 2
#define N_MEM 32
#define BATCH 1024
#define PAIR_PER_HOP (BATCH * N_MEM)       // 32768
#define N_PAIR (N_HOP * PAIR_PER_HOP)      // 65536
#define CAP 3072                           // per-relation bucket capacity (mean 2048)
#define JBLK 32                            // blocks per relation in pairs kernel
#define WPB 4                              // waves per block
#define NBLK_PAIRS (JBLK * N_REL * WPB)    // 4096 per-wave reduction slots

typedef __attribute__((ext_vector_type(8))) short short8;   // 8 bf16 (A/B frag)
typedef __attribute__((ext_vector_type(4))) float floatx4;  // C/D frag

__device__ __forceinline__ float wave_reduce_sum(float v) {
    v += __shfl_xor(v, 1);
    v += __shfl_xor(v, 2);
    v += __shfl_xor(v, 4);
    v += __shfl_xor(v, 8);
    v += __shfl_xor(v, 16);
    v += __shfl_xor(v, 32);
    return v;
}

__device__ __forceinline__ unsigned short f2b(float x) {
    union { float f; unsigned u; } c; c.f = x;
    const unsigned r = (c.u + 0x7FFFu + ((c.u >> 16) & 1u)) >> 16;
    return (unsigned short)r;
}

__device__ __forceinline__ short8 pack8(const float4 a, const float4 b) {
    short8 s;
    s[0] = (short)f2b(a.x); s[1] = (short)f2b(a.y);
    s[2] = (short)f2b(a.z); s[3] = (short)f2b(a.w);
    s[4] = (short)f2b(b.x); s[5] = (short)f2b(b.y);
    s[6] = (short)f2b(b.z); s[7] = (short)f2b(b.w);
    return s;
}

__device__ __forceinline__ float sq4(const float4 a) {
    return a.x * a.x + a.y * a.y + a.z * a.z + a.w * a.w;
}

// ---------------------------------------------------------------------------
// K0: bucket pair indices by relation (g_cnt zeroed by hipMemsetAsync first).
// ---------------------------------------------------------------------------
__global__ __launch_bounds__(256) void ripple_bin(
    const int* __restrict__ mr,
    int* __restrict__ g_cnt,     // [N_REL]
    int* __restrict__ list)      // [N_REL][CAP]
{
    __shared__ int hist[N_REL];
    __shared__ int cur[N_REL];
    const int tid = (int)threadIdx.x;
    const int pbase = (int)blockIdx.x * 1024;

    if (tid < N_REL) hist[tid] = 0;
    __syncthreads();

    int rv[4];
    #pragma unroll
    for (int u = 0; u < 4; ++u) {
        rv[u] = mr[pbase + u * 256 + tid];
        atomicAdd(&hist[rv[u]], 1);
    }
    __syncthreads();
    if (tid < N_REL) cur[tid] = atomicAdd(&g_cnt[tid], hist[tid]);
    __syncthreads();
    #pragma unroll
    for (int u = 0; u < 4; ++u) {
        const int r = rv[u];
        const int pos = atomicAdd(&cur[r], 1);
        if (pos < CAP) list[r * CAP + pos] = pbase + u * 256 + tid;
    }
}

// ---------------------------------------------------------------------------
// K1: MFMA gather-GEMM pairs kernel.
// Per 16-pair tile of relation r: A_h/A_t (16x64) gathered in A-frag layout,
// B = R^T in VGPRs, 16x mfma -> Rh, Rt. Epilogue (C layout, 8 interleaved
// butterfly chains): hRt -> KGE; v0.Rh -> hop0 logits (stored to wsL);
// hop1 Rh stored to wsRh. Index chase prefetched across tiles.
// ---------------------------------------------------------------------------
__global__ __launch_bounds__(256) void ripple_pairs(
    const int* __restrict__ items,
    const int* __restrict__ mh,
    const int* __restrict__ mt,
    const float* __restrict__ item_table,
    const float* __restrict__ rel_table,
    const int* __restrict__ g_cnt,
    const int* __restrict__ list,
    float* __restrict__ wsL,      // [PAIR_PER_HOP] hop0 logits
    float* __restrict__ wsRh,     // [PAIR_PER_HOP][DIM] hop1 Rh
    float* __restrict__ ws_kge,   // [NBLK_PAIRS]
    float* __restrict__ ws_l2)    // [NBLK_PAIRS]
{
    const int tid = (int)threadIdx.x;
    const int lane = tid & 63;
    const int w = tid >> 6;
    const int j = (int)blockIdx.x;
    const int r = (int)blockIdx.y;
    const int n = min(g_cnt[r], CAP);

    const int m16 = lane & 15;
    const int quad = lane >> 4;
    const int rb = r * CAP;
    const int wave_id = j * WPB + w;

    // ---- first-tile index chase, issued BEFORE B setup (latency overlap) ----
    int tau = wave_id;
    int p = 0, hidx = 0, tidx = 0;
    if (tau * 16 < n) {
        const int pos = min(tau * 16 + m16, n - 1);
        p = list[rb + pos];
        hidx = mh[p];
        tidx = mt[p];
    }

    // ---- B = R^T fragments ----
    short8 Bf[2][4];
    float rsq = 0.f;
    {
        const float* __restrict__ Rb = rel_table + (size_t)r * (DIM * DIM);
        #pragma unroll
        for (int s = 0; s < 2; ++s) {
            #pragma unroll
            for (int tn = 0; tn < 4; ++tn) {
                const float* src = Rb + (size_t)(16 * tn + m16) * DIM + 32 * s + 8 * quad;
                const float4 a = *(const float4*)src;
                const float4 b = *(const float4*)(src + 4);
                rsq += sq4(a) + sq4(b);
                Bf[s][tn] = pack8(a, b);
            }
        }
    }

    float kge = 0.f;
    float l2ht = 0.f;
    int cnt = 0;

    for (; tau * 16 < n; tau += JBLK * WPB) {
        const int base = tau * 16;
        const bool mvalid = (base + m16) < n;

        // ---- A rows ----
        const float* __restrict__ hp = item_table + (size_t)hidx * DIM + 8 * quad;
        const float* __restrict__ tp = item_table + (size_t)tidx * DIM + 8 * quad;
        const float4 h0a = *(const float4*)hp;
        const float4 h0b = *(const float4*)(hp + 4);
        const float4 h1a = *(const float4*)(hp + 32);
        const float4 h1b = *(const float4*)(hp + 36);
        const float4 t0a = *(const float4*)tp;
        const float4 t0b = *(const float4*)(tp + 4);
        const float4 t1a = *(const float4*)(tp + 32);
        const float4 t1b = *(const float4*)(tp + 36);

        // ---- prefetch next tile's indices ----
        const int tau2 = tau + JBLK * WPB;
        int p2 = 0, h2 = 0, t2 = 0;
        if (tau2 * 16 < n) {
            const int pos2 = min(tau2 * 16 + m16, n - 1);
            p2 = list[rb + pos2];
            h2 = mh[p2];
            t2 = mt[p2];
        }

        if (mvalid) {
            l2ht += sq4(h0a) + sq4(h0b) + sq4(h1a) + sq4(h1b)
                  + sq4(t0a) + sq4(t0b) + sq4(t1a) + sq4(t1b);
        }

        const short8 Ah0 = pack8(h0a, h0b);
        const short8 Ah1 = pack8(h1a, h1b);
        const short8 At0 = pack8(t0a, t0b);
        const short8 At1 = pack8(t1a, t1b);

        floatx4 Ch[4], Ct[4];
        const floatx4 z4 = {0.f, 0.f, 0.f, 0.f};
        #pragma unroll
        for (int tn = 0; tn < 4; ++tn) {
            Ch[tn] = __builtin_amdgcn_mfma_f32_16x16x32_bf16(Ah0, Bf[0][tn], z4, 0, 0, 0);
            Ch[tn] = __builtin_amdgcn_mfma_f32_16x16x32_bf16(Ah1, Bf[1][tn], Ch[tn], 0, 0, 0);
            Ct[tn] = __builtin_amdgcn_mfma_f32_16x16x32_bf16(At0, Bf[0][tn], z4, 0, 0, 0);
            Ct[tn] = __builtin_amdgcn_mfma_f32_16x16x32_bf16(At1, Bf[1][tn], Ct[tn], 0, 0, 0);
        }

        // ---- redistribute indices into C layout (slot = 4*quad + q) ----
        int pq[4], hq[4], iq[4];
        bool hop0[4];
        #pragma unroll
        for (int q = 0; q < 4; ++q) {
            pq[q] = __shfl(p, 4 * quad + q);
            hq[q] = __shfl(hidx, 4 * quad + q);
            hop0[q] = pq[q] < PAIR_PER_HOP;
            iq[q] = items[min(pq[q] >> 5, BATCH - 1)];   // clamp keeps load safe
        }

        // ---- hRt (KGE) + v0.Rh (hop0 logits): 8 interleaved chains ----
        float accT[4] = {0.f, 0.f, 0.f, 0.f};
        float accL[4] = {0.f, 0.f, 0.f, 0.f};
        #pragma unroll
        for (int tn = 0; tn < 4; ++tn) {
            const int col = m16 + 16 * tn;
            #pragma unroll
            for (int q = 0; q < 4; ++q) {
                accT[q] = fmaf(item_table[(size_t)hq[q] * DIM + col], Ct[tn][q], accT[q]);
                if (hop0[q])
                    accL[q] = fmaf(item_table[(size_t)iq[q] * DIM + col], Ch[tn][q], accL[q]);
            }
        }
        #pragma unroll
        for (int s = 1; s <= 8; s <<= 1) {
            #pragma unroll
            for (int q = 0; q < 4; ++q) {
                accT[q] += __shfl_xor(accT[q], s);
                accL[q] += __shfl_xor(accL[q], s);
            }
        }
        #pragma unroll
        for (int q = 0; q < 4; ++q) {
            const bool pv = (base + 4 * quad + q) < n;
            const float sg = 1.f / (1.f + expf(-accT[q]));
            if (pv && m16 == 0) kge += sg;
            if (hop0[q] && m16 == 0) wsL[pq[q]] = accL[q];  // dup tail: same value
        }

        // ---- hop1 Rh stores only ----
        #pragma unroll
        for (int tn = 0; tn < 4; ++tn) {
            #pragma unroll
            for (int q = 0; q < 4; ++q) {
                if (!hop0[q])
                    wsRh[(size_t)(pq[q] - PAIR_PER_HOP) * DIM + m16 + 16 * tn] = Ch[tn][q];
            }
        }

        cnt += min(16, n - base);
        p = p2; hidx = h2; tidx = t2;
    }

    const float Rsum = wave_reduce_sum(rsq);
    const float l2tot = wave_reduce_sum(l2ht) + (float)cnt * Rsum;
    const float kgetot = wave_reduce_sum(kge);
    if (lane == 0) {
        const int bid = (r * JBLK + j) * WPB + w;
        ws_kge[bid] = kgetot;
        ws_l2[bid] = l2tot;
    }
}

// ---------------------------------------------------------------------------
// K2: per-batch attention chain. hop0 logits precomputed (wsL); hop1 logits
// computed 8-threads-per-slot in one parallel pass from wsRh and LDS v1.
// ---------------------------------------------------------------------------
__global__ __launch_bounds__(256) void ripple_attn(
    const int* __restrict__ items,
    const float* __restrict__ labels,
    const int* __restrict__ mt,
    const float* __restrict__ item_table,
    const float* __restrict__ W,
    const float* __restrict__ wsL,
    const float* __restrict__ wsRh,
    float* __restrict__ out,
    float* __restrict__ ws_bce)
{
    __shared__ float sAtt[N_MEM];
    __shared__ __align__(16) float sO[4][DIM];
    __shared__ __align__(16) float sU[DIM];
    __shared__ __align__(16) float sV[DIM];

    const int b = (int)blockIdx.x;
    const int tid = (int)threadIdx.x;
    const int lane = tid & 63;
    const int w = tid >> 6;

    float v_i = item_table[(size_t)items[b] * DIM + lane];
    float y_i = 0.f;

    for (int hop = 0; hop < N_HOP; ++hop) {
        if (hop == 0) {
            if (tid < N_MEM) sAtt[tid] = wsL[b * N_MEM + tid];
        } else {
            // one parallel pass: thread t -> slot m=t>>3, dims 8*(t&7)..+8
            const int m = tid >> 3;
            const int d0 = (tid & 7) * 8;
            const float* __restrict__ rp =
                wsRh + (size_t)(b * N_MEM + m) * DIM + d0;
            const float4 ra = *(const float4*)rp;
            const float4 rb4 = *(const float4*)(rp + 4);
            const float4 va = *(const float4*)&sV[d0];
            const float4 vb = *(const float4*)&sV[d0 + 4];
            float dp = ra.x * va.x + ra.y * va.y + ra.z * va.z + ra.w * va.w
                     + rb4.x * vb.x + rb4.y * vb.y + rb4.z * vb.z + rb4.w * vb.w;
            dp += __shfl_xor(dp, 1);
            dp += __shfl_xor(dp, 2);
            dp += __shfl_xor(dp, 4);
            if ((tid & 7) == 0) sAtt[m] = dp;
        }
        __syncthreads();

        float mx = -1e30f;
        #pragma unroll
        for (int m = 0; m < N_MEM; ++m) mx = fmaxf(mx, sAtt[m]);
        float se = 0.f;
        float e_loc[8];
        #pragma unroll
        for (int m = 0; m < N_MEM; ++m) {
            const float e = expf(sAtt[m] - mx);
            se += e;
            if ((m >> 3) == w) e_loc[m & 7] = e;
        }
        const float inv = 1.f / se;

        float op = 0.f;
        #pragma unroll
        for (int q = 0; q < 8; ++q) {
            const int m = w * 8 + q;
            const int tidx = mt[hop * PAIR_PER_HOP + b * N_MEM + m];
            op = fmaf(item_table[(size_t)tidx * DIM + lane], e_loc[q] * inv, op);
        }
        sO[w][lane] = op;
        __syncthreads();

        const float o_i = sO[0][lane] + sO[1][lane] + sO[2][lane] + sO[3][lane];
        y_i += o_i;
        if (w == 0) sU[lane] = v_i + o_i;
        __syncthreads();

        const float4* __restrict__ Wrow = (const float4*)(W + (size_t)lane * DIM);
        float a0 = 0.f, a1 = 0.f, a2 = 0.f, a3 = 0.f;
        #pragma unroll
        for (int k = 0; k < 16; ++k) {
            const float4 w4 = Wrow[k];
            const float4 u4 = *(const float4*)&sU[k * 4];
            a0 = fmaf(w4.x, u4.x, a0);
            a1 = fmaf(w4.y, u4.y, a1);
            a2 = fmaf(w4.z, u4.z, a2);
            a3 = fmaf(w4.w, u4.w, a3);
        }
        v_i = (a0 + a1) + (a2 + a3);
        if (w == 0) sV[lane] = v_i;     // v1 for hop1 logit pass
        __syncthreads();
    }

    float s = wave_reduce_sum(v_i * y_i);
    s = 1.f / (1.f + expf(-s));
    if (tid == 0) {
        out[b] = s;
        const float lab = labels[b];
        const float logp = fmaxf(logf(s), -100.f);
        const float lognp = fmaxf(logf(1.f - s), -100.f);
        ws_bce[b] = lab * logp + (1.f - lab) * lognp;
    }
}

// ---------------------------------------------------------------------------
// K3: loss finalize.
// ---------------------------------------------------------------------------
__global__ __launch_bounds__(256) void ripple_finalize(
    const float* __restrict__ ws_bce,
    const float* __restrict__ ws_kge,
    const float* __restrict__ ws_l2,
    float* __restrict__ out)
{
    __shared__ float sb[4], sk[4], sl[4];
    const int tid = (int)threadIdx.x;
    float bsum = 0.f, ksum = 0.f, lsum = 0.f;
    for (int i = tid; i < BATCH; i += 256) bsum += ws_bce[i];
    for (int i = tid; i < NBLK_PAIRS; i += 256) {
        ksum += ws_kge[i];
        lsum += ws_l2[i];
    }
    bsum = wave_reduce_sum(bsum);
    ksum = wave_reduce_sum(ksum);
    lsum = wave_reduce_sum(lsum);
    const int w = tid >> 6;
    if ((tid & 63) == 0) { sb[w] = bsum; sk[w] = ksum; sl[w] = lsum; }
    __syncthreads();
    if (tid == 0) {
        const float bs = sb[0] + sb[1] + sb[2] + sb[3];
        const float ks = sk[0] + sk[1] + sk[2] + sk[3];
        const float ls = sl[0] + sl[1] + sl[2] + sl[3];
        const float base_loss = -bs / (float)BATCH;
        const float kge_loss = -0.01f * (ks / (float)(BATCH * N_MEM));
        const float l2_loss = 1e-7f * ls;
        out[BATCH + 0] = base_loss + kge_loss + l2_loss;
        out[BATCH + 1] = base_loss;
        out[BATCH + 2] = kge_loss;
        out[BATCH + 3] = l2_loss;
    }
}

extern "C" void kernel_launch(void* const* d_in, const int* in_sizes, int n_in,
                              void* d_out, int out_size, void* d_ws, size_t ws_size,
                              hipStream_t stream) {
    const int* items        = (const int*)d_in[0];
    const float* labels     = (const float*)d_in[1];
    const int* mh           = (const int*)d_in[2];
    const int* mr           = (const int*)d_in[3];
    const int* mt           = (const int*)d_in[4];
    const float* item_table = (const float*)d_in[5];
    const float* rel_table  = (const float*)d_in[6];
    const float* W          = (const float*)d_in[7];
    float* out = (float*)d_out;

    // workspace: wsL[32768] | wsRh[32768*64] | list[N_REL*CAP] | g_cnt[N_REL]
    //            | ws_bce[BATCH] | ws_kge[NBLK_PAIRS] | ws_l2[NBLK_PAIRS]
    float* ws = (float*)d_ws;
    float* wsL    = ws;
    float* wsRh   = wsL + PAIR_PER_HOP;
    int*   list   = (int*)(wsRh + (size_t)PAIR_PER_HOP * DIM);
    int*   g_cnt  = list + N_REL * CAP;
    float* ws_bce = (float*)(g_cnt + N_REL);
    float* ws_kge = ws_bce + BATCH;
    float* ws_l2  = ws_kge + NBLK_PAIRS;

    hipMemsetAsync(g_cnt, 0, N_REL * sizeof(int), stream);
    ripple_bin<<<N_PAIR / 1024, 256, 0, stream>>>(mr, g_cnt, list);
    dim3 gpairs(JBLK, N_REL);
    ripple_pairs<<<gpairs, 256, 0, stream>>>(items, mh, mt, item_table, rel_table,
                                             g_cnt, list, wsL, wsRh, ws_kge, ws_l2);
    ripple_attn<<<BATCH, 256, 0, stream>>>(items, labels, mt, item_table, W,
                                           wsL, wsRh, out, ws_bce);
    ripple_finalize<<<1, 256, 0, stream>>>(ws_bce, ws_kge, ws_l2, out);
}

// Round 6
// 144.563 us; speedup vs baseline: 1.4320x; 1.0504x over previous
//
#include <hip/hip_runtime.h>
#include <math.h>

#define N_ENTITY 200000
#define N_REL 32
#define DIM 64
#define N_HOP 2
#define N_MEM 32
#define BATCH 1024
#define PAIR_PER_HOP (BATCH * N_MEM)       // 32768
#define N_PAIR (N_HOP * PAIR_PER_HOP)      // 65536
#define CAP 3072                           // per-relation bucket capacity (mean 2048)
#define JBLK 32                            // blocks per relation in pairs kernel
#define WPB 4                              // waves per block
#define NBLK_PAIRS (JBLK * N_REL * WPB)    // 4096 per-wave reduction slots
#define TPAD 68                            // LDS transpose row pitch (16B-aligned, conflict-friendly)

typedef __attribute__((ext_vector_type(8))) short short8;   // 8 bf16 (A/B frag)
typedef __attribute__((ext_vector_type(4))) float floatx4;  // C/D frag

__device__ __forceinline__ float wave_reduce_sum(float v) {
    v += __shfl_xor(v, 1);
    v += __shfl_xor(v, 2);
    v += __shfl_xor(v, 4);
    v += __shfl_xor(v, 8);
    v += __shfl_xor(v, 16);
    v += __shfl_xor(v, 32);
    return v;
}

__device__ __forceinline__ unsigned short f2b(float x) {
    union { float f; unsigned u; } c; c.f = x;
    const unsigned r = (c.u + 0x7FFFu + ((c.u >> 16) & 1u)) >> 16;
    return (unsigned short)r;
}

__device__ __forceinline__ short8 pack8(const float4 a, const float4 b) {
    short8 s;
    s[0] = (short)f2b(a.x); s[1] = (short)f2b(a.y);
    s[2] = (short)f2b(a.z); s[3] = (short)f2b(a.w);
    s[4] = (short)f2b(b.x); s[5] = (short)f2b(b.y);
    s[6] = (short)f2b(b.z); s[7] = (short)f2b(b.w);
    return s;
}

__device__ __forceinline__ float sq4(const float4 a) {
    return a.x * a.x + a.y * a.y + a.z * a.z + a.w * a.w;
}

__device__ __forceinline__ float dot4(const float4 a, const float4 b) {
    return a.x * b.x + a.y * b.y + a.z * b.z + a.w * b.w;
}

// ---------------------------------------------------------------------------
// K0: bucket pair indices by relation (g_cnt zeroed by hipMemsetAsync first).
// ---------------------------------------------------------------------------
__global__ __launch_bounds__(256) void ripple_bin(
    const int* __restrict__ mr,
    int* __restrict__ g_cnt,     // [N_REL]
    int* __restrict__ list)      // [N_REL][CAP]
{
    __shared__ int hist[N_REL];
    __shared__ int cur[N_REL];
    const int tid = (int)threadIdx.x;
    const int pbase = (int)blockIdx.x * 1024;

    if (tid < N_REL) hist[tid] = 0;
    __syncthreads();

    int rv[4];
    #pragma unroll
    for (int u = 0; u < 4; ++u) {
        rv[u] = mr[pbase + u * 256 + tid];
        atomicAdd(&hist[rv[u]], 1);
    }
    __syncthreads();
    if (tid < N_REL) cur[tid] = atomicAdd(&g_cnt[tid], hist[tid]);
    __syncthreads();
    #pragma unroll
    for (int u = 0; u < 4; ++u) {
        const int r = rv[u];
        const int pos = atomicAdd(&cur[r], 1);
        if (pos < CAP) list[r * CAP + pos] = pbase + u * 256 + tid;
    }
}

// ---------------------------------------------------------------------------
// K1: MFMA gather-GEMM pairs kernel with LDS-transpose epilogue.
// Per 16-pair tile of relation r: A_h/A_t (16x64) gathered in A-frag layout,
// B = R^T in VGPRs, 16x mfma -> Ch (Rh), Ct (Rt) in C layout. Both are
// round-tripped through wave-private LDS into row-major [pair][col] so that
// lane (quad,m16) owns pair m16 — matching the original per-lane p/hidx
// (no shfl redistribution, no scattered global re-reads):
//   hRt  = fp32-register h . Ct  -> KGE (quad-reduce, 1 expf/lane)
//   v0.Ch -> hop0 logit (4 masked float4 v0 gathers)
//   Ch   -> wsRh (hop1) as 4 b128 stores
// ---------------------------------------------------------------------------
__global__ __launch_bounds__(256) void ripple_pairs(
    const int* __restrict__ items,
    const int* __restrict__ mh,
    const int* __restrict__ mt,
    const float* __restrict__ item_table,
    const float* __restrict__ rel_table,
    const int* __restrict__ g_cnt,
    const int* __restrict__ list,
    float* __restrict__ wsL,      // [PAIR_PER_HOP] hop0 logits
    float* __restrict__ wsRh,     // [PAIR_PER_HOP][DIM] hop1 Rh
    float* __restrict__ ws_kge,   // [NBLK_PAIRS]
    float* __restrict__ ws_l2)    // [NBLK_PAIRS]
{
    __shared__ __align__(16) float sTr[WPB][2][16 * TPAD];  // ~34 KB: [wave][Ch|Ct]

    const int tid = (int)threadIdx.x;
    const int lane = tid & 63;
    const int w = tid >> 6;
    const int j = (int)blockIdx.x;
    const int r = (int)blockIdx.y;
    const int n = min(g_cnt[r], CAP);

    const int m16 = lane & 15;
    const int quad = lane >> 4;
    const int rb = r * CAP;
    const int wave_id = j * WPB + w;

    float* __restrict__ bufC = &sTr[w][0][0];
    float* __restrict__ bufT = &sTr[w][1][0];

    // ---- first-tile index chase, issued BEFORE B setup (latency overlap) ----
    int tau = wave_id;
    int p = 0, hidx = 0, tidx = 0;
    if (tau * 16 < n) {
        const int pos = min(tau * 16 + m16, n - 1);
        p = list[rb + pos];              // same p across the 4 quads of m16
        hidx = mh[p];
        tidx = mt[p];
    }

    // ---- B = R^T fragments ----
    short8 Bf[2][4];
    float rsq = 0.f;
    {
        const float* __restrict__ Rb = rel_table + (size_t)r * (DIM * DIM);
        #pragma unroll
        for (int s = 0; s < 2; ++s) {
            #pragma unroll
            for (int tn = 0; tn < 4; ++tn) {
                const float* src = Rb + (size_t)(16 * tn + m16) * DIM + 32 * s + 8 * quad;
                const float4 a = *(const float4*)src;
                const float4 b = *(const float4*)(src + 4);
                rsq += sq4(a) + sq4(b);
                Bf[s][tn] = pack8(a, b);
            }
        }
    }

    float kge = 0.f;
    float l2ht = 0.f;
    int cnt = 0;

    for (; tau * 16 < n; tau += JBLK * WPB) {
        const int base = tau * 16;
        const bool mvalid = (base + m16) < n;

        // ---- A rows (row = m16, cols 8q..8q+7 and 32+8q..+7) ----
        const float* __restrict__ hp = item_table + (size_t)hidx * DIM + 8 * quad;
        const float* __restrict__ tp = item_table + (size_t)tidx * DIM + 8 * quad;
        const float4 h0a = *(const float4*)hp;
        const float4 h0b = *(const float4*)(hp + 4);
        const float4 h1a = *(const float4*)(hp + 32);
        const float4 h1b = *(const float4*)(hp + 36);
        const float4 t0a = *(const float4*)tp;
        const float4 t0b = *(const float4*)(tp + 4);
        const float4 t1a = *(const float4*)(tp + 32);
        const float4 t1b = *(const float4*)(tp + 36);

        // ---- prefetch next tile's indices ----
        const int tau2 = tau + JBLK * WPB;
        int p2 = 0, h2 = 0, t2 = 0;
        if (tau2 * 16 < n) {
            const int pos2 = min(tau2 * 16 + m16, n - 1);
            p2 = list[rb + pos2];
            h2 = mh[p2];
            t2 = mt[p2];
        }

        if (mvalid) {
            l2ht += sq4(h0a) + sq4(h0b) + sq4(h1a) + sq4(h1b)
                  + sq4(t0a) + sq4(t0b) + sq4(t1a) + sq4(t1b);
        }

        const short8 Ah0 = pack8(h0a, h0b);
        const short8 Ah1 = pack8(h1a, h1b);
        const short8 At0 = pack8(t0a, t0b);
        const short8 At1 = pack8(t1a, t1b);

        floatx4 Ch[4], Ct[4];
        const floatx4 z4 = {0.f, 0.f, 0.f, 0.f};
        #pragma unroll
        for (int tn = 0; tn < 4; ++tn) {
            Ch[tn] = __builtin_amdgcn_mfma_f32_16x16x32_bf16(Ah0, Bf[0][tn], z4, 0, 0, 0);
            Ch[tn] = __builtin_amdgcn_mfma_f32_16x16x32_bf16(Ah1, Bf[1][tn], Ch[tn], 0, 0, 0);
            Ct[tn] = __builtin_amdgcn_mfma_f32_16x16x32_bf16(At0, Bf[0][tn], z4, 0, 0, 0);
            Ct[tn] = __builtin_amdgcn_mfma_f32_16x16x32_bf16(At1, Bf[1][tn], Ct[tn], 0, 0, 0);
        }

        // ---- LDS transpose: C layout (row=4*quad+q, col=m16+16tn) -> [row][col] ----
        // write banks: (16*quad + m16) % 32 -> exactly 2-way (free)
        #pragma unroll
        for (int tn = 0; tn < 4; ++tn) {
            const int col = m16 + 16 * tn;
            #pragma unroll
            for (int q = 0; q < 4; ++q) {
                const int row = 4 * quad + q;
                bufC[row * TPAD + col] = Ch[tn][q];
                bufT[row * TPAD + col] = Ct[tn][q];
            }
        }

        // ---- hRt: Ct row-readback in A-frag-matching cols, dot fp32 h regs ----
        const float* rowT = bufT + m16 * TPAD;
        const float4 ct0 = *(const float4*)(rowT + 8 * quad);
        const float4 ct1 = *(const float4*)(rowT + 8 * quad + 4);
        const float4 ct2 = *(const float4*)(rowT + 32 + 8 * quad);
        const float4 ct3 = *(const float4*)(rowT + 32 + 8 * quad + 4);
        float hrt = dot4(h0a, ct0) + dot4(h0b, ct1) + dot4(h1a, ct2) + dot4(h1b, ct3);
        hrt += __shfl_xor(hrt, 16);
        hrt += __shfl_xor(hrt, 32);

        // ---- Ch row-readback (cols 16*quad .. +15) ----
        const float* rowC = bufC + m16 * TPAD;
        const float4 c0 = *(const float4*)(rowC + 16 * quad);
        const float4 c1 = *(const float4*)(rowC + 16 * quad + 4);
        const float4 c2 = *(const float4*)(rowC + 16 * quad + 8);
        const float4 c3 = *(const float4*)(rowC + 16 * quad + 12);

        // ---- hop0 logit: v0 . Ch (v0 gathered in same row layout, masked) ----
        const bool hop0 = p < PAIR_PER_HOP;
        float lg = 0.f;
        if (hop0) {
            const float* __restrict__ vp =
                item_table + (size_t)items[p >> 5] * DIM + 16 * quad;
            lg = dot4(*(const float4*)vp, c0)
               + dot4(*(const float4*)(vp + 4), c1)
               + dot4(*(const float4*)(vp + 8), c2)
               + dot4(*(const float4*)(vp + 12), c3);
        }
        lg += __shfl_xor(lg, 16);
        lg += __shfl_xor(lg, 32);

        if (quad == 0 && mvalid) {
            kge += 1.f / (1.f + expf(-hrt));
            if (hop0) wsL[p] = lg;
        }

        // ---- hop1 Rh store: 4 x b128, lane owns pair m16's cols 16q..+15 ----
        if (mvalid && !hop0) {
            float* __restrict__ dst =
                wsRh + (size_t)(p - PAIR_PER_HOP) * DIM + 16 * quad;
            *(float4*)dst = c0;
            *(float4*)(dst + 4) = c1;
            *(float4*)(dst + 8) = c2;
            *(float4*)(dst + 12) = c3;
        }

        cnt += min(16, n - base);
        p = p2; hidx = h2; tidx = t2;
    }

    const float Rsum = wave_reduce_sum(rsq);
    const float l2tot = wave_reduce_sum(l2ht) + (float)cnt * Rsum;
    const float kgetot = wave_reduce_sum(kge);
    if (lane == 0) {
        const int bid = (r * JBLK + j) * WPB + w;
        ws_kge[bid] = kgetot;
        ws_l2[bid] = l2tot;
    }
}

// ---------------------------------------------------------------------------
// K2: per-batch attention chain (unchanged from R5).
// ---------------------------------------------------------------------------
__global__ __launch_bounds__(256) void ripple_attn(
    const int* __restrict__ items,
    const float* __restrict__ labels,
    const int* __restrict__ mt,
    const float* __restrict__ item_table,
    const float* __restrict__ W,
    const float* __restrict__ wsL,
    const float* __restrict__ wsRh,
    float* __restrict__ out,
    float* __restrict__ ws_bce)
{
    __shared__ float sAtt[N_MEM];
    __shared__ __align__(16) float sO[4][DIM];
    __shared__ __align__(16) float sU[DIM];
    __shared__ __align__(16) float sV[DIM];

    const int b = (int)blockIdx.x;
    const int tid = (int)threadIdx.x;
    const int lane = tid & 63;
    const int w = tid >> 6;

    float v_i = item_table[(size_t)items[b] * DIM + lane];
    float y_i = 0.f;

    for (int hop = 0; hop < N_HOP; ++hop) {
        if (hop == 0) {
            if (tid < N_MEM) sAtt[tid] = wsL[b * N_MEM + tid];
        } else {
            const int m = tid >> 3;
            const int d0 = (tid & 7) * 8;
            const float* __restrict__ rp =
                wsRh + (size_t)(b * N_MEM + m) * DIM + d0;
            const float4 ra = *(const float4*)rp;
            const float4 rb4 = *(const float4*)(rp + 4);
            const float4 va = *(const float4*)&sV[d0];
            const float4 vb = *(const float4*)&sV[d0 + 4];
            float dp = ra.x * va.x + ra.y * va.y + ra.z * va.z + ra.w * va.w
                     + rb4.x * vb.x + rb4.y * vb.y + rb4.z * vb.z + rb4.w * vb.w;
            dp += __shfl_xor(dp, 1);
            dp += __shfl_xor(dp, 2);
            dp += __shfl_xor(dp, 4);
            if ((tid & 7) == 0) sAtt[m] = dp;
        }
        __syncthreads();

        float mx = -1e30f;
        #pragma unroll
        for (int m = 0; m < N_MEM; ++m) mx = fmaxf(mx, sAtt[m]);
        float se = 0.f;
        float e_loc[8];
        #pragma unroll
        for (int m = 0; m < N_MEM; ++m) {
            const float e = expf(sAtt[m] - mx);
            se += e;
            if ((m >> 3) == w) e_loc[m & 7] = e;
        }
        const float inv = 1.f / se;

        float op = 0.f;
        #pragma unroll
        for (int q = 0; q < 8; ++q) {
            const int m = w * 8 + q;
            const int tidx = mt[hop * PAIR_PER_HOP + b * N_MEM + m];
            op = fmaf(item_table[(size_t)tidx * DIM + lane], e_loc[q] * inv, op);
        }
        sO[w][lane] = op;
        __syncthreads();

        const float o_i = sO[0][lane] + sO[1][lane] + sO[2][lane] + sO[3][lane];
        y_i += o_i;
        if (w == 0) sU[lane] = v_i + o_i;
        __syncthreads();

        const float4* __restrict__ Wrow = (const float4*)(W + (size_t)lane * DIM);
        float a0 = 0.f, a1 = 0.f, a2 = 0.f, a3 = 0.f;
        #pragma unroll
        for (int k = 0; k < 16; ++k) {
            const float4 w4 = Wrow[k];
            const float4 u4 = *(const float4*)&sU[k * 4];
            a0 = fmaf(w4.x, u4.x, a0);
            a1 = fmaf(w4.y, u4.y, a1);
            a2 = fmaf(w4.z, u4.z, a2);
            a3 = fmaf(w4.w, u4.w, a3);
        }
        v_i = (a0 + a1) + (a2 + a3);
        if (w == 0) sV[lane] = v_i;
        __syncthreads();
    }

    float s = wave_reduce_sum(v_i * y_i);
    s = 1.f / (1.f + expf(-s));
    if (tid == 0) {
        out[b] = s;
        const float lab = labels[b];
        const float logp = fmaxf(logf(s), -100.f);
        const float lognp = fmaxf(logf(1.f - s), -100.f);
        ws_bce[b] = lab * logp + (1.f - lab) * lognp;
    }
}

// ---------------------------------------------------------------------------
// K3: loss finalize.
// ---------------------------------------------------------------------------
__global__ __launch_bounds__(256) void ripple_finalize(
    const float* __restrict__ ws_bce,
    const float* __restrict__ ws_kge,
    const float* __restrict__ ws_l2,
    float* __restrict__ out)
{
    __shared__ float sb[4], sk[4], sl[4];
    const int tid = (int)threadIdx.x;
    float bsum = 0.f, ksum = 0.f, lsum = 0.f;
    for (int i = tid; i < BATCH; i += 256) bsum += ws_bce[i];
    for (int i = tid; i < NBLK_PAIRS; i += 256) {
        ksum += ws_kge[i];
        lsum += ws_l2[i];
    }
    bsum = wave_reduce_sum(bsum);
    ksum = wave_reduce_sum(ksum);
    lsum = wave_reduce_sum(lsum);
    const int w = tid >> 6;
    if ((tid & 63) == 0) { sb[w] = bsum; sk[w] = ksum; sl[w] = lsum; }
    __syncthreads();
    if (tid == 0) {
        const float bs = sb[0] + sb[1] + sb[2] + sb[3];
        const float ks = sk[0] + sk[1] + sk[2] + sk[3];
        const float ls = sl[0] + sl[1] + sl[2] + sl[3];
        const float base_loss = -bs / (float)BATCH;
        const float kge_loss = -0.01f * (ks / (float)(BATCH * N_MEM));
        const float l2_loss = 1e-7f * ls;
        out[BATCH + 0] = base_loss + kge_loss + l2_loss;
        out[BATCH + 1] = base_loss;
        out[BATCH + 2] = kge_loss;
        out[BATCH + 3] = l2_loss;
    }
}

extern "C" void kernel_launch(void* const* d_in, const int* in_sizes, int n_in,
                              void* d_out, int out_size, void* d_ws, size_t ws_size,
                              hipStream_t stream) {
    const int* items        = (const int*)d_in[0];
    const float* labels     = (const float*)d_in[1];
    const int* mh           = (const int*)d_in[2];
    const int* mr           = (const int*)d_in[3];
    const int* mt           = (const int*)d_in[4];
    const float* item_table = (const float*)d_in[5];
    const float* rel_table  = (const float*)d_in[6];
    const float* W          = (const float*)d_in[7];
    float* out = (float*)d_out;

    // workspace: wsL[32768] | wsRh[32768*64] | list[N_REL*CAP] | g_cnt[N_REL]
    //            | ws_bce[BATCH] | ws_kge[NBLK_PAIRS] | ws_l2[NBLK_PAIRS]
    float* ws = (float*)d_ws;
    float* wsL    = ws;
    float* wsRh   = wsL + PAIR_PER_HOP;
    int*   list   = (int*)(wsRh + (size_t)PAIR_PER_HOP * DIM);
    int*   g_cnt  = list + N_REL * CAP;
    float* ws_bce = (float*)(g_cnt + N_REL);
    float* ws_kge = ws_bce + BATCH;
    float* ws_l2  = ws_kge + NBLK_PAIRS;

    hipMemsetAsync(g_cnt, 0, N_REL * sizeof(int), stream);
    ripple_bin<<<N_PAIR / 1024, 256, 0, stream>>>(mr, g_cnt, list);
    dim3 gpairs(JBLK, N_REL);
    ripple_pairs<<<gpairs, 256, 0, stream>>>(items, mh, mt, item_table, rel_table,
                                             g_cnt, list, wsL, wsRh, ws_kge, ws_l2);
    ripple_attn<<<BATCH, 256, 0, stream>>>(items, labels, mt, item_table, W,
                                           wsL, wsRh, out, ws_bce);
    ripple_finalize<<<1, 256, 0, stream>>>(ws_bce, ws_kge, ws_l2, out);
}